// Round 1
// baseline (503.948 us; speedup 1.0000x reference)
//
#include <hip/hip_runtime.h>
#include <math.h>

#define NB 16
#define NCH 9
#define PI2 6.28318530717958647692f

struct MixArgs {
  const float* in[3];
  const float* w[12];
  float* out[3];
};
struct GhArgs {
  const float* z6[2];
  const float* low[2];
  const float* lob[2];
  float* out[2];
  int acc[2];
};

// ---------------- twiddle tables ----------------
// twt: [5][64][2] = (cos, sin)(2*pi*k*t/64)
// twx: per level lev (n=32>>lev): [kn][n][2] = (cos,sin)(2*pi*k_j*m/n), 640 floats/level
__global__ __launch_bounds__(256) void k_init(float* __restrict__ twt, float* __restrict__ twx) {
  int tid = threadIdx.x;
  for (int i = tid; i < 5 * 64; i += 256) {
    int k = i >> 6, t = i & 63;
    float ang = (float)((k * t) & 63) * (PI2 / 64.f);
    float s, c;
    sincosf(ang, &s, &c);
    twt[2 * i] = c;
    twt[2 * i + 1] = s;
  }
  for (int lev = 0; lev < 6; ++lev) {
    int n = 32 >> lev;
    int kn = n < 10 ? n : 10;
    float* tx = twx + lev * 640;
    for (int i = tid; i < kn * n; i += 256) {
      int j = i / n, m = i % n;
      int k = (kn < 10) ? j : (j < 5 ? j : n - 10 + j);
      float ang = (float)((k * m) % n) * (PI2 / (float)n);
      float s, c;
      sincosf(ang, &s, &c);
      tx[2 * i] = c;
      tx[2 * i + 1] = s;
    }
  }
}

// ---------------- wavelet analysis: gather quadrants + ec_d/ec_s (36->9) ----------------
// xin: [NB][9][2n][2n][64] -> dout,sout: [NB][9][n][n][64]
__global__ __launch_bounds__(256) void k_wavelet(const float* __restrict__ xin,
                                                 const float* __restrict__ ecd,
                                                 const float* __restrict__ ecs,
                                                 float* __restrict__ dout,
                                                 float* __restrict__ sout, int n) {
  long pos = (long)blockIdx.x * 4 + threadIdx.x / 64;
  long total = (long)NB * n * n;
  if (pos >= total) return;
  int t = threadIdx.x & 63;
  int b = (int)(pos / (n * n));
  int rem = (int)(pos % (n * n));
  int xp = rem / n, yp = rem % n;
  int n2 = 2 * n;
  const float* xb = xin + (long)b * NCH * n2 * n2 * 64;
  float dacc[9], sacc[9];
#pragma unroll
  for (int o = 0; o < 9; ++o) { dacc[o] = 0.f; sacc[o] = 0.f; }
#pragma unroll
  for (int q = 0; q < 4; ++q) {
    int X = 2 * xp + (q >> 1), Y = 2 * yp + (q & 1);
    const float* xq = xb + ((long)X * n2 + Y) * 64 + t;
#pragma unroll
    for (int i = 0; i < 9; ++i) {
      float v = xq[(long)i * n2 * n2 * 64];
#pragma unroll
      for (int o = 0; o < 9; ++o) {
        dacc[o] += v * ecd[(q * 9 + i) * 9 + o];
        sacc[o] += v * ecs[(q * 9 + i) * 9 + o];
      }
    }
  }
  long cs = (long)n * n * 64;
  float* dp = dout + (long)b * NCH * cs + (long)rem * 64 + t;
  float* sp = sout + (long)b * NCH * cs + (long)rem * 64 + t;
#pragma unroll
  for (int o = 0; o < 9; ++o) { dp[o * cs] = dacc[o]; sp[o * cs] = sacc[o]; }
}

// ---------------- forward t-DFT (real -> 5 complex modes), ortho scale folded ----------------
// in: [NB][9][n][n][64] -> Z: [NB][9][n][n][5] cplx   (grid.y: 0=d, 1=s)
__global__ __launch_bounds__(256) void k_dft_t(const float* __restrict__ dIn,
                                               const float* __restrict__ sIn,
                                               float* __restrict__ Zd, float* __restrict__ Zs,
                                               const float* __restrict__ twt, int n,
                                               float scale) {
  const float* in = blockIdx.y ? sIn : dIn;
  float* out = blockIdx.y ? Zs : Zd;
  long row = (long)blockIdx.x * 256 + threadIdx.x;
  long nrows = (long)NB * NCH * n * n;
  if (row >= nrows) return;
  const float4* p4 = reinterpret_cast<const float4*>(in + row * 64);
  float ar[5] = {0, 0, 0, 0, 0}, ai[5] = {0, 0, 0, 0, 0};
#pragma unroll
  for (int tq = 0; tq < 16; ++tq) {
    float4 v4 = p4[tq];
    float vv[4] = {v4.x, v4.y, v4.z, v4.w};
#pragma unroll
    for (int j = 0; j < 4; ++j) {
      int t = 4 * tq + j;
      float v = vv[j];
#pragma unroll
      for (int k = 0; k < 5; ++k) {
        ar[k] += v * twt[2 * (k * 64 + t)];       // Re += x*cos
        ai[k] -= v * twt[2 * (k * 64 + t) + 1];   // Im -= x*sin   (e^{-i})
      }
    }
  }
  float* o = out + row * 10;
#pragma unroll
  for (int k = 0; k < 5; ++k) { o[2 * k] = ar[k] * scale; o[2 * k + 1] = ai[k] * scale; }
}

// ---------------- forward y-DFT then x-DFT ----------------
// in: [bc][x][y][5] cplx -> out: [bc][jx][jy][5] cplx ; block per bc, grid.y: d/s
__global__ __launch_bounds__(256) void k_bc(const float* __restrict__ Zd,
                                            const float* __restrict__ Zs,
                                            float* __restrict__ Od, float* __restrict__ Os,
                                            const float* __restrict__ twx, int n, int kn) {
  __shared__ float S1[3200];
  __shared__ float tx[640];
  int tid = threadIdx.x;
  for (int i = tid; i < kn * n * 2; i += 256) tx[i] = twx[i];
  __syncthreads();
  const float* in = (blockIdx.y ? Zs : Zd) + (long)blockIdx.x * n * n * 10;
  float* out = (blockIdx.y ? Os : Od) + (long)blockIdx.x * kn * kn * 10;
  int s1n = n * kn * 5;
  for (int idx = tid; idx < s1n; idx += 256) {
    int kz = idx % 5, jy = (idx / 5) % kn, x = idx / (5 * kn);
    float sr = 0.f, si = 0.f;
    const float* row = in + (long)x * n * 10 + 2 * kz;
    for (int y = 0; y < n; ++y) {
      float zr = row[y * 10], zi = row[y * 10 + 1];
      float c = tx[2 * (jy * n + y)], s = tx[2 * (jy * n + y) + 1];
      sr += zr * c + zi * s;   // (zr+i zi)(c - i s)
      si += zi * c - zr * s;
    }
    S1[2 * idx] = sr;
    S1[2 * idx + 1] = si;
  }
  __syncthreads();
  int s2n = kn * kn * 5;
  for (int idx = tid; idx < s2n; idx += 256) {
    int kz = idx % 5, jy = (idx / 5) % kn, jx = idx / (5 * kn);
    float sr = 0.f, si = 0.f;
    for (int x = 0; x < n; ++x) {
      float zr = S1[2 * ((x * kn + jy) * 5 + kz)], zi = S1[2 * ((x * kn + jy) * 5 + kz) + 1];
      float c = tx[2 * (jx * n + x)], s = tx[2 * (jx * n + x) + 1];
      sr += zr * c + zi * s;
      si += zi * c - zr * s;
    }
    out[2 * idx] = sr;
    out[2 * idx + 1] = si;
  }
}

// ---------------- quadrant mode-mix (complex 9x9), overwrite precedence w4>w3>w2>w1 ----------
// in: [b][i][jx][jy][kz] cplx -> out: [b][o][jx][jy][kz] cplx ; grid.y: 0=a(d),1=b(s),2=c(d)
__global__ __launch_bounds__(256) void k_mix(MixArgs args, int n, int kn) {
  int batch = blockIdx.y;
  const float* in = args.in[batch];
  float* out = args.out[batch];
  int nm = kn * kn * 5;
  long idx = (long)blockIdx.x * 256 + threadIdx.x;
  long total = (long)NB * nm * 9;
  if (idx >= total) return;
  int o = (int)(idx % 9);
  long r = idx / 9;
  int m = (int)(r % nm);
  int b = (int)(r / nm);
  int kz = m % 5, jy = (m / 5) % kn, jx = m / (5 * kn);
  int l1 = (5 < n / 2 + 1) ? 5 : n / 2 + 1;
  int kx = (kn < 10) ? jx : (jx < 5 ? jx : n - 10 + jx);
  int ky = (kn < 10) ? jy : (jy < 5 ? jy : n - 10 + jy);
  bool lx = kx < l1, hx = kx >= n - l1, ly = ky < l1, hy = ky >= n - l1;
  const float* wsel;
  int wx, wy;
  if (hx && hy) { wsel = args.w[batch * 4 + 3]; wx = kx - (n - l1); wy = ky - (n - l1); }
  else if (lx && hy) { wsel = args.w[batch * 4 + 2]; wx = kx; wy = ky - (n - l1); }
  else if (hx && ly) { wsel = args.w[batch * 4 + 1]; wx = kx - (n - l1); wy = ky; }
  else { wsel = args.w[batch * 4 + 0]; wx = kx; wy = ky; }
  // w layout [i][o][wx][wy][wz][2]; strides: i 2250, o 250, wx 50, wy 10, wz 2
  const float* wp = wsel + o * 250 + wx * 50 + wy * 10 + kz * 2;
  const float* ip = in + (long)b * 9 * nm * 2 + m * 2;
  float sr = 0.f, si = 0.f;
#pragma unroll
  for (int i = 0; i < 9; ++i) {
    float arv = ip[(long)i * nm * 2], aiv = ip[(long)i * nm * 2 + 1];
    float wr = wp[i * 2250], wi = wp[i * 2250 + 1];
    sr += arv * wr - aiv * wi;
    si += arv * wi + aiv * wr;
  }
  out[((long)b * 9 + o) * nm * 2 + m * 2] = sr;
  out[((long)b * 9 + o) * nm * 2 + m * 2 + 1] = si;
}

// ---------------- inverse expand x then y ----------------
// in: [bo][jx][jy][kz] cplx -> out Z6: [bo][x][y][kz] cplx ; grid.y: a/b/c
__global__ __launch_bounds__(256) void k_ef(const float* __restrict__ Za,
                                            const float* __restrict__ Zb,
                                            const float* __restrict__ Zc,
                                            float* __restrict__ O6a, float* __restrict__ O6b,
                                            float* __restrict__ O6c,
                                            const float* __restrict__ twx, int n, int kn) {
  __shared__ float zm[1000];
  __shared__ float S1[3200];
  __shared__ float tx[640];
  int tid = threadIdx.x;
  int nm = kn * kn * 5;
  const float* in =
      (blockIdx.y == 0 ? Za : blockIdx.y == 1 ? Zb : Zc) + (long)blockIdx.x * nm * 2;
  float* out =
      (blockIdx.y == 0 ? O6a : blockIdx.y == 1 ? O6b : O6c) + (long)blockIdx.x * n * n * 10;
  for (int i = tid; i < kn * n * 2; i += 256) tx[i] = twx[i];
  for (int i = tid; i < nm * 2; i += 256) zm[i] = in[i];
  __syncthreads();
  int s1n = n * kn * 5;
  for (int idx = tid; idx < s1n; idx += 256) {
    int kz = idx % 5, jy = (idx / 5) % kn, x = idx / (5 * kn);
    float sr = 0.f, si = 0.f;
    for (int jx = 0; jx < kn; ++jx) {
      float zr = zm[2 * ((jx * kn + jy) * 5 + kz)], zi = zm[2 * ((jx * kn + jy) * 5 + kz) + 1];
      float c = tx[2 * (jx * n + x)], s = tx[2 * (jx * n + x) + 1];
      sr += zr * c - zi * s;   // (zr+i zi)(c + i s)
      si += zr * s + zi * c;
    }
    S1[2 * idx] = sr;
    S1[2 * idx + 1] = si;
  }
  __syncthreads();
  int s2n = n * n * 5;
  for (int idx = tid; idx < s2n; idx += 256) {
    int kz = idx % 5, y = (idx / 5) % n, x = idx / (5 * n);
    float sr = 0.f, si = 0.f;
    for (int jy = 0; jy < kn; ++jy) {
      float zr = S1[2 * ((x * kn + jy) * 5 + kz)], zi = S1[2 * ((x * kn + jy) * 5 + kz) + 1];
      float c = tx[2 * (jy * n + y)], s = tx[2 * (jy * n + y) + 1];
      sr += zr * c - zi * s;
      si += zr * s + zi * c;
    }
    out[2 * idx] = sr;
    out[2 * idx + 1] = si;
  }
}

// ---------------- inverse t (c2r) + ReLU + lo conv (9x9) + bias, set or accumulate --------
__global__ __launch_bounds__(256) void k_gh(GhArgs a, const float* __restrict__ twt, int n,
                                            float scale) {
  int batch = blockIdx.y;
  const float* z6 = a.z6[batch];
  const float* low = a.low[batch];
  const float* lob = a.lob[batch];
  float* out = a.out[batch];
  int acc = a.acc[batch];
  __shared__ float tw[640];
  __shared__ float zz[4 * 9 * 10];
  int tid = threadIdx.x;
  for (int i = tid; i < 640; i += 256) tw[i] = twt[i];
  long pos0 = (long)blockIdx.x * 4;
  long total = (long)NB * n * n;
  for (int i = tid; i < 4 * 90; i += 256) {
    int p = i / 90, rest = i % 90;
    long pos = pos0 + p;
    if (pos < total) {
      int b = (int)(pos / (n * n));
      int rem = (int)(pos % (n * n));
      int ch = rest / 10, zi = rest % 10;
      zz[i] = z6[((long)(b * 9 + ch) * n * n + rem) * 10 + zi];
    }
  }
  __syncthreads();
  int p = tid / 64, t = tid & 63;
  long pos = pos0 + p;
  if (pos >= total) return;
  int b = (int)(pos / (n * n));
  int rem = (int)(pos % (n * n));
  float rv[9];
#pragma unroll
  for (int i = 0; i < 9; ++i) {
    const float* zp = &zz[p * 90 + i * 10];
    float v = zp[0];  // k=0: theta=0 -> Re only (Im of DC bin ignored, matches c2r)
#pragma unroll
    for (int k = 1; k < 5; ++k) {
      float c = tw[2 * (k * 64 + t)], s = tw[2 * (k * 64 + t) + 1];
      v += 2.f * (zp[2 * k] * c - zp[2 * k + 1] * s);
    }
    v *= scale;
    rv[i] = fmaxf(v, 0.f);
  }
  long cs = (long)n * n * 64;
  long ob = (long)b * 9 * cs + (long)rem * 64 + t;
#pragma unroll
  for (int o = 0; o < 9; ++o) {
    float sum = lob[o];
#pragma unroll
    for (int i = 0; i < 9; ++i) sum += low[o * 9 + i] * rv[i];
    if (acc)
      out[ob + o * cs] += sum;
    else
      out[ob + o * cs] = sum;
  }
}

// ---------------- coarsest-level T0 1x1 conv ----------------
__global__ __launch_bounds__(64) void k_t0(const float* __restrict__ sin_,
                                           const float* __restrict__ w,
                                           const float* __restrict__ bias,
                                           float* __restrict__ out) {
  int b = blockIdx.x, t = threadIdx.x;
  float v[9];
#pragma unroll
  for (int i = 0; i < 9; ++i) v[i] = sin_[((long)b * 9 + i) * 64 + t];
#pragma unroll
  for (int o = 0; o < 9; ++o) {
    float s = bias[o];
#pragma unroll
    for (int i = 0; i < 9; ++i) s += w[o * 9 + i] * v[i];
    out[((long)b * 9 + o) * 64 + t] = s;
  }
}

// ---------------- reconstruction: x+Us, cat Ud, 4x (18->9), spatial interleave ------------
__global__ __launch_bounds__(256) void k_recon(const float* __restrict__ xc,
                                               const float* __restrict__ Us,
                                               const float* __restrict__ Ud,
                                               const float* __restrict__ ree,
                                               const float* __restrict__ reo,
                                               const float* __restrict__ roe,
                                               const float* __restrict__ roo,
                                               float* __restrict__ out, int n) {
  long pos = (long)blockIdx.x * 4 + threadIdx.x / 64;
  long total = (long)NB * n * n;
  if (pos >= total) return;
  int t = threadIdx.x & 63;
  int b = (int)(pos / (n * n));
  int rem = (int)(pos % (n * n));
  int xp = rem / n, yp = rem % n;
  long cs = (long)n * n * 64;
  long ib = (long)b * 9 * cs + (long)rem * 64 + t;
  float cat[18];
#pragma unroll
  for (int i = 0; i < 9; ++i) cat[i] = xc[ib + i * cs] + Us[ib + i * cs];
#pragma unroll
  for (int i = 0; i < 9; ++i) cat[9 + i] = Ud[ib + i * cs];
  int n2 = 2 * n;
  long ocs = (long)n2 * n2 * 64;
  long ob = (long)b * 9 * ocs + ((long)(2 * xp) * n2 + 2 * yp) * 64 + t;
  const float* rcw[4] = {ree, reo, roe, roo};
#pragma unroll
  for (int r = 0; r < 4; ++r) {
    int rx = r >> 1, ry = r & 1;
    long obb = ob + ((long)rx * n2 + ry) * 64;
    const float* wp = rcw[r];
#pragma unroll
    for (int o = 0; o < 9; ++o) {
      float s = 0.f;
#pragma unroll
      for (int i = 0; i < 18; ++i) s += cat[i] * wp[i * 9 + o];
      out[obb + o * ocs] = s;
    }
  }
}

extern "C" void kernel_launch(void* const* d_in, const int* in_sizes, int n_in, void* d_out,
                              int out_size, void* d_ws, size_t ws_size, hipStream_t stream) {
  (void)in_sizes; (void)n_in; (void)out_size; (void)ws_size;
  const float* x = (const float*)d_in[0];
  const float* aw[4] = {(const float*)d_in[1], (const float*)d_in[2], (const float*)d_in[3],
                        (const float*)d_in[4]};
  const float* a_low = (const float*)d_in[5];
  const float* a_lob = (const float*)d_in[6];
  const float* bw[4] = {(const float*)d_in[7], (const float*)d_in[8], (const float*)d_in[9],
                        (const float*)d_in[10]};
  const float* b_low = (const float*)d_in[11];
  const float* b_lob = (const float*)d_in[12];
  const float* cw[4] = {(const float*)d_in[13], (const float*)d_in[14], (const float*)d_in[15],
                        (const float*)d_in[16]};
  const float* c_low = (const float*)d_in[17];
  const float* c_lob = (const float*)d_in[18];
  const float* t0w = (const float*)d_in[19];
  const float* t0b = (const float*)d_in[20];
  const float* ecs = (const float*)d_in[21];
  const float* ecd = (const float*)d_in[22];
  const float* rcee = (const float*)d_in[23];
  const float* rceo = (const float*)d_in[24];
  const float* rcoe = (const float*)d_in[25];
  const float* rcoo = (const float*)d_in[26];

  float* ws = (float*)d_ws;
  size_t off = 0;
  float* twt = ws + off; off += 640;
  float* twx = ws + off; off += 6 * 640;
  float* dbuf = ws + off; off += 9437184;
  float* s_a = ws + off; off += 9437184;
  float* s_b = ws + off; off += 9437184;
  float* Ud = ws + off; off += 12579840;
  float* Us = ws + off; off += 12579840;
  float* Zt_d = ws + off; off += 1474560;
  float* Zt_s = ws + off; off += 1474560;
  float* Zxy_d = ws + off; off += 144000;
  float* Zxy_s = ws + off; off += 144000;
  float* Zm0 = ws + off; off += 144000;
  float* Zm1 = ws + off; off += 144000;
  float* Zm2 = ws + off; off += 144000;
  float* Z60 = ws + off; off += 1474560;
  float* Z61 = ws + off; off += 1474560;
  float* Z62 = ws + off; off += 1474560;

  static const long lvl_off[6] = {0, 9437184, 11796480, 12386304, 12533760, 12570624};

  k_init<<<1, 256, 0, stream>>>(twt, twx);

  const float* cur = x;
  for (int lev = 0; lev < 6; ++lev) {
    int n = 32 >> lev;
    int kn = n < 10 ? n : 10;
    float* s_cur = (lev & 1) ? s_b : s_a;
    int nblk = (NB * n * n + 3) / 4;
    k_wavelet<<<nblk, 256, 0, stream>>>(cur, ecd, ecs, dbuf, s_cur, n);

    float scale = 1.f / sqrtf((float)(n * n * 64));
    long nrows = (long)NB * NCH * n * n;
    k_dft_t<<<dim3((unsigned)((nrows + 255) / 256), 2), 256, 0, stream>>>(dbuf, s_cur, Zt_d,
                                                                          Zt_s, twt, n, scale);
    k_bc<<<dim3(NB * NCH, 2), 256, 0, stream>>>(Zt_d, Zt_s, Zxy_d, Zxy_s, twx + lev * 640, n,
                                                kn);
    MixArgs ma;
    ma.in[0] = Zxy_d; ma.in[1] = Zxy_s; ma.in[2] = Zxy_d;
    for (int j = 0; j < 4; ++j) { ma.w[j] = aw[j]; ma.w[4 + j] = bw[j]; ma.w[8 + j] = cw[j]; }
    ma.out[0] = Zm0; ma.out[1] = Zm1; ma.out[2] = Zm2;
    long mtotal = (long)NB * kn * kn * 5 * 9;
    k_mix<<<dim3((unsigned)((mtotal + 255) / 256), 3), 256, 0, stream>>>(ma, n, kn);
    k_ef<<<dim3(NB * NCH, 3), 256, 0, stream>>>(Zm0, Zm1, Zm2, Z60, Z61, Z62, twx + lev * 640,
                                                n, kn);
    GhArgs g1;
    g1.z6[0] = Z60; g1.z6[1] = Z62;
    g1.low[0] = a_low; g1.low[1] = c_low;
    g1.lob[0] = a_lob; g1.lob[1] = c_lob;
    g1.out[0] = Ud + lvl_off[lev]; g1.out[1] = Us + lvl_off[lev];
    g1.acc[0] = 0; g1.acc[1] = 0;
    k_gh<<<dim3(nblk, 2), 256, 0, stream>>>(g1, twt, n, scale);
    GhArgs g2;
    g2.z6[0] = Z61; g2.z6[1] = Z61;
    g2.low[0] = b_low; g2.low[1] = b_low;
    g2.lob[0] = b_lob; g2.lob[1] = b_lob;
    g2.out[0] = Ud + lvl_off[lev]; g2.out[1] = Ud + lvl_off[lev];
    g2.acc[0] = 1; g2.acc[1] = 1;
    k_gh<<<dim3(nblk, 1), 256, 0, stream>>>(g2, twt, n, scale);
    cur = s_cur;
  }

  // coarsest-level conv (cur == s_b after lev 5)
  k_t0<<<NB, 64, 0, stream>>>(cur, t0w, t0b, dbuf);

  const float* rx = dbuf;
  for (int i = 5; i >= 0; --i) {
    int nn = 32 >> i;
    float* dst = (i == 0) ? (float*)d_out : ((rx == dbuf) ? s_a : dbuf);
    k_recon<<<(NB * nn * nn + 3) / 4, 256, 0, stream>>>(rx, Us + lvl_off[i], Ud + lvl_off[i],
                                                        rcee, rceo, rcoe, rcoo, dst, nn);
    rx = dst;
  }
}

// Round 2
// 393.559 us; speedup vs baseline: 1.2805x; 1.2805x over previous
//
#include <hip/hip_runtime.h>
#include <math.h>

#define NB 16
#define NCH 9
#define PI2 6.28318530717958647692f

struct EfArgs {
  const float* in[3];
  const float* w[12];
  float* out[3];
};

// ---------------- twiddle tables ----------------
// twt: [5][64][2] = (cos, sin)(2*pi*k*t/64)
// twx: per level lev (n=32>>lev): [kn][n][2] = (cos,sin)(2*pi*k_j*m/n), 640 floats/level
__global__ __launch_bounds__(256) void k_init(float* __restrict__ twt, float* __restrict__ twx) {
  int tid = threadIdx.x;
  for (int i = tid; i < 5 * 64; i += 256) {
    int k = i >> 6, t = i & 63;
    float ang = (float)((k * t) & 63) * (PI2 / 64.f);
    float s, c;
    sincosf(ang, &s, &c);
    twt[2 * i] = c;
    twt[2 * i + 1] = s;
  }
  for (int lev = 0; lev < 6; ++lev) {
    int n = 32 >> lev;
    int kn = n < 10 ? n : 10;
    float* tx = twx + lev * 640;
    for (int i = tid; i < kn * n; i += 256) {
      int j = i / n, m = i % n;
      int k = (kn < 10) ? j : (j < 5 ? j : n - 10 + j);
      float ang = (float)((k * m) % n) * (PI2 / (float)n);
      float s, c;
      sincosf(ang, &s, &c);
      tx[2 * i] = c;
      tx[2 * i + 1] = s;
    }
  }
}

// ---------------- fused wavelet analysis + forward t-DFT ----------------
// xin: [NB][9][2n][2n][64] -> sout: [NB][9][n][n][64] (global, needed next level)
//                             Zd,Zs: [NB][9][n][n][5] cplx (ortho scale folded)
__global__ __launch_bounds__(256) void k_wavdft(const float* __restrict__ xin,
                                                const float* __restrict__ ecd,
                                                const float* __restrict__ ecs,
                                                float* __restrict__ sout,
                                                float* __restrict__ Zd, float* __restrict__ Zs,
                                                const float* __restrict__ twt, int n,
                                                float scale) {
  __shared__ float V[72 * 65];  // (p*18 + ds*9 + ch)*65 + t
  __shared__ float tw[640];
  int tid = threadIdx.x;
  for (int i = tid; i < 640; i += 256) tw[i] = twt[i];
  long pos0 = (long)blockIdx.x * 4;
  long total = (long)NB * n * n;
  int p = tid >> 6, t = tid & 63;
  long pos = pos0 + p;
  if (pos < total) {
    int b = (int)(pos / (n * n));
    int rem = (int)(pos % (n * n));
    int xp = rem / n, yp = rem % n;
    int n2 = 2 * n;
    const float* xb = xin + (long)b * NCH * n2 * n2 * 64;
    float dacc[9], sacc[9];
#pragma unroll
    for (int o = 0; o < 9; ++o) { dacc[o] = 0.f; sacc[o] = 0.f; }
#pragma unroll
    for (int q = 0; q < 4; ++q) {
      int X = 2 * xp + (q >> 1), Y = 2 * yp + (q & 1);
      const float* xq = xb + ((long)X * n2 + Y) * 64 + t;
#pragma unroll
      for (int i = 0; i < 9; ++i) {
        float v = xq[(long)i * n2 * n2 * 64];
#pragma unroll
        for (int o = 0; o < 9; ++o) {
          dacc[o] += v * ecd[(q * 9 + i) * 9 + o];
          sacc[o] += v * ecs[(q * 9 + i) * 9 + o];
        }
      }
    }
    long cs = (long)n * n * 64;
    float* sp = sout + (long)b * NCH * cs + (long)rem * 64 + t;
#pragma unroll
    for (int o = 0; o < 9; ++o) {
      sp[o * cs] = sacc[o];
      V[(p * 18 + o) * 65 + t] = dacc[o];
      V[(p * 18 + 9 + o) * 65 + t] = sacc[o];
    }
  }
  __syncthreads();
  // phase 2: 5-mode t-DFT from LDS. tasks: (p, ds, ch, k) = 4*2*9*5 = 360
  for (int idx = tid; idx < 360; idx += 256) {
    int k = idx % 5;
    int ch = (idx / 5) % 9;
    int ds = (idx / 45) & 1;
    int pp = idx / 90;
    long pos2 = pos0 + pp;
    if (pos2 >= total) continue;
    const float* vr = &V[(pp * 18 + ds * 9 + ch) * 65];
    float sr = 0.f, si = 0.f;
#pragma unroll 8
    for (int tt = 0; tt < 64; ++tt) {
      float v = vr[tt];
      sr += v * tw[2 * (k * 64 + tt)];
      si -= v * tw[2 * (k * 64 + tt) + 1];
    }
    int b = (int)(pos2 / (n * n));
    int rem = (int)(pos2 % (n * n));
    float* o = (ds ? Zs : Zd) + ((long)(b * 9 + ch) * n * n + rem) * 10 + 2 * k;
    o[0] = sr * scale;
    o[1] = si * scale;
  }
}

// ---------------- forward y-DFT then x-DFT ----------------
// in: [bc][x][y][5] cplx -> out: [bc][jx][jy][5] cplx ; block per bc, grid.y: d/s
__global__ __launch_bounds__(256) void k_bc(const float* __restrict__ Zd,
                                            const float* __restrict__ Zs,
                                            float* __restrict__ Od, float* __restrict__ Os,
                                            const float* __restrict__ twx, int n, int kn) {
  __shared__ float S1[3200];
  __shared__ float tx[640];
  int tid = threadIdx.x;
  for (int i = tid; i < kn * n * 2; i += 256) tx[i] = twx[i];
  __syncthreads();
  const float* in = (blockIdx.y ? Zs : Zd) + (long)blockIdx.x * n * n * 10;
  float* out = (blockIdx.y ? Os : Od) + (long)blockIdx.x * kn * kn * 10;
  int s1n = n * kn * 5;
  for (int idx = tid; idx < s1n; idx += 256) {
    int kz = idx % 5, jy = (idx / 5) % kn, x = idx / (5 * kn);
    float sr = 0.f, si = 0.f;
    const float* row = in + (long)x * n * 10 + 2 * kz;
    for (int y = 0; y < n; ++y) {
      float zr = row[y * 10], zi = row[y * 10 + 1];
      float c = tx[2 * (jy * n + y)], s = tx[2 * (jy * n + y) + 1];
      sr += zr * c + zi * s;  // (zr+i zi)(c - i s)
      si += zi * c - zr * s;
    }
    S1[2 * idx] = sr;
    S1[2 * idx + 1] = si;
  }
  __syncthreads();
  int s2n = kn * kn * 5;
  for (int idx = tid; idx < s2n; idx += 256) {
    int kz = idx % 5, jy = (idx / 5) % kn, jx = idx / (5 * kn);
    float sr = 0.f, si = 0.f;
    for (int x = 0; x < n; ++x) {
      float zr = S1[2 * ((x * kn + jy) * 5 + kz)], zi = S1[2 * ((x * kn + jy) * 5 + kz) + 1];
      float c = tx[2 * (jx * n + x)], s = tx[2 * (jx * n + x) + 1];
      sr += zr * c + zi * s;
      si += zi * c - zr * s;
    }
    out[2 * idx] = sr;
    out[2 * idx + 1] = si;
  }
}

// ---------------- fused quadrant mode-mix + inverse expand x,y ----------------
// block per (b, out-ch o); grid.y: 0=a(d), 1=b(s), 2=c(d)
// in: [b][i][jx][jy][kz] cplx -> out Z6: [b][o][x][y][kz] cplx
__global__ __launch_bounds__(256) void k_efmix(EfArgs a, const float* __restrict__ twx, int n,
                                               int kn) {
  __shared__ float zin[9000];
  __shared__ float zm[1000];
  __shared__ float S1[3200];
  __shared__ float tx[640];
  int tid = threadIdx.x;
  int batch = blockIdx.y;
  int b = blockIdx.x / 9, o = blockIdx.x % 9;
  int nm = kn * kn * 5;
  const float* in = a.in[batch] + (long)b * 9 * nm * 2;
  float* out = a.out[batch] + ((long)(b * 9 + o)) * n * n * 10;
  for (int i = tid; i < kn * n * 2; i += 256) tx[i] = twx[i];
  for (int i = tid; i < 9 * nm * 2; i += 256) zin[i] = in[i];
  __syncthreads();
  // mix: zm[m] = sum_i zin[i][m] * w[i][o][modes(m)], overwrite precedence w4>w3>w2>w1
  int l1 = (5 < n / 2 + 1) ? 5 : n / 2 + 1;
  for (int m = tid; m < nm; m += 256) {
    int kz = m % 5, jy = (m / 5) % kn, jx = m / (5 * kn);
    int kx = (kn < 10) ? jx : (jx < 5 ? jx : n - 10 + jx);
    int ky = (kn < 10) ? jy : (jy < 5 ? jy : n - 10 + jy);
    bool lx = kx < l1, hx = kx >= n - l1, ly = ky < l1, hy = ky >= n - l1;
    const float* wsel;
    int wx, wy;
    if (hx && hy) { wsel = a.w[batch * 4 + 3]; wx = kx - (n - l1); wy = ky - (n - l1); }
    else if (lx && hy) { wsel = a.w[batch * 4 + 2]; wx = kx; wy = ky - (n - l1); }
    else if (hx && ly) { wsel = a.w[batch * 4 + 1]; wx = kx - (n - l1); wy = ky; }
    else { wsel = a.w[batch * 4 + 0]; wx = kx; wy = ky; }
    // w layout [i][o][wx][wy][wz][2]; strides: i 2250, o 250, wx 50, wy 10, wz 2
    const float* wp = wsel + o * 250 + wx * 50 + wy * 10 + kz * 2;
    float sr = 0.f, si = 0.f;
#pragma unroll
    for (int i = 0; i < 9; ++i) {
      float ar = zin[(i * nm + m) * 2], ai = zin[(i * nm + m) * 2 + 1];
      float wr = wp[i * 2250], wi = wp[i * 2250 + 1];
      sr += ar * wr - ai * wi;
      si += ar * wi + ai * wr;
    }
    zm[2 * m] = sr;
    zm[2 * m + 1] = si;
  }
  __syncthreads();
  // expand x
  int s1n = n * kn * 5;
  for (int idx = tid; idx < s1n; idx += 256) {
    int kz = idx % 5, jy = (idx / 5) % kn, x = idx / (5 * kn);
    float sr = 0.f, si = 0.f;
    for (int jx = 0; jx < kn; ++jx) {
      float zr = zm[2 * ((jx * kn + jy) * 5 + kz)], zi = zm[2 * ((jx * kn + jy) * 5 + kz) + 1];
      float c = tx[2 * (jx * n + x)], s = tx[2 * (jx * n + x) + 1];
      sr += zr * c - zi * s;  // (zr+i zi)(c + i s)
      si += zr * s + zi * c;
    }
    S1[2 * idx] = sr;
    S1[2 * idx + 1] = si;
  }
  __syncthreads();
  // expand y
  int s2n = n * n * 5;
  for (int idx = tid; idx < s2n; idx += 256) {
    int kz = idx % 5, y = (idx / 5) % n, x = idx / (5 * n);
    float sr = 0.f, si = 0.f;
    for (int jy = 0; jy < kn; ++jy) {
      float zr = S1[2 * ((x * kn + jy) * 5 + kz)], zi = S1[2 * ((x * kn + jy) * 5 + kz) + 1];
      float c = tx[2 * (jy * n + y)], s = tx[2 * (jy * n + y) + 1];
      sr += zr * c - zi * s;
      si += zr * s + zi * c;
    }
    out[2 * idx] = sr;
    out[2 * idx + 1] = si;
  }
}

// ---------------- fused inverse-t(c2r) + ReLU + lo conv for Ud AND Us ----------------
// Ud = A(Z60)+B(Z61) (both biases), Us = C(Z62)
__global__ __launch_bounds__(256) void k_gh3(const float* __restrict__ Z60,
                                             const float* __restrict__ Z61,
                                             const float* __restrict__ Z62,
                                             const float* __restrict__ a_low,
                                             const float* __restrict__ a_lob,
                                             const float* __restrict__ b_low,
                                             const float* __restrict__ b_lob,
                                             const float* __restrict__ c_low,
                                             const float* __restrict__ c_lob,
                                             float* __restrict__ Ud, float* __restrict__ Us,
                                             const float* __restrict__ twt, int n,
                                             float scale) {
  __shared__ float tw[640];
  __shared__ float zz[3][360];  // [buf][p*90 + ch*10 + zi]
  int tid = threadIdx.x;
  for (int i = tid; i < 640; i += 256) tw[i] = twt[i];
  long pos0 = (long)blockIdx.x * 4;
  long total = (long)NB * n * n;
  const float* zbuf[3] = {Z60, Z61, Z62};
  for (int i = tid; i < 3 * 360; i += 256) {
    int bi = i / 360, rest = i % 360;
    int p = rest / 90, rr = rest % 90;
    long pos = pos0 + p;
    if (pos < total) {
      int b = (int)(pos / (n * n));
      int rem = (int)(pos % (n * n));
      int ch = rr / 10, zi = rr % 10;
      zz[bi][rest] = zbuf[bi][((long)(b * 9 + ch) * n * n + rem) * 10 + zi];
    }
  }
  __syncthreads();
  int p = tid / 64, t = tid & 63;
  long pos = pos0 + p;
  if (pos >= total) return;
  int b = (int)(pos / (n * n));
  int rem = (int)(pos % (n * n));
  float rva[9], rvb[9], rvc[9];
#pragma unroll
  for (int i = 0; i < 9; ++i) {
    const float* za = &zz[0][p * 90 + i * 10];
    const float* zb = &zz[1][p * 90 + i * 10];
    const float* zc = &zz[2][p * 90 + i * 10];
    float va = za[0], vb = zb[0], vc = zc[0];  // k=0: Im of DC bin ignored (matches c2r)
#pragma unroll
    for (int k = 1; k < 5; ++k) {
      float c = tw[2 * (k * 64 + t)], s = tw[2 * (k * 64 + t) + 1];
      va += 2.f * (za[2 * k] * c - za[2 * k + 1] * s);
      vb += 2.f * (zb[2 * k] * c - zb[2 * k + 1] * s);
      vc += 2.f * (zc[2 * k] * c - zc[2 * k + 1] * s);
    }
    rva[i] = fmaxf(va * scale, 0.f);
    rvb[i] = fmaxf(vb * scale, 0.f);
    rvc[i] = fmaxf(vc * scale, 0.f);
  }
  long cs = (long)n * n * 64;
  long ob = (long)b * 9 * cs + (long)rem * 64 + t;
#pragma unroll
  for (int o = 0; o < 9; ++o) {
    float du = a_lob[o] + b_lob[o];
    float us = c_lob[o];
#pragma unroll
    for (int i = 0; i < 9; ++i) {
      du += a_low[o * 9 + i] * rva[i] + b_low[o * 9 + i] * rvb[i];
      us += c_low[o * 9 + i] * rvc[i];
    }
    Ud[ob + o * cs] = du;
    Us[ob + o * cs] = us;
  }
}

// ---------------- coarsest-level T0 1x1 conv ----------------
__global__ __launch_bounds__(64) void k_t0(const float* __restrict__ sin_,
                                           const float* __restrict__ w,
                                           const float* __restrict__ bias,
                                           float* __restrict__ out) {
  int b = blockIdx.x, t = threadIdx.x;
  float v[9];
#pragma unroll
  for (int i = 0; i < 9; ++i) v[i] = sin_[((long)b * 9 + i) * 64 + t];
#pragma unroll
  for (int o = 0; o < 9; ++o) {
    float s = bias[o];
#pragma unroll
    for (int i = 0; i < 9; ++i) s += w[o * 9 + i] * v[i];
    out[((long)b * 9 + o) * 64 + t] = s;
  }
}

// ---------------- reconstruction: x+Us, cat Ud, 4x (18->9), spatial interleave ------------
__global__ __launch_bounds__(256) void k_recon(const float* __restrict__ xc,
                                               const float* __restrict__ Us,
                                               const float* __restrict__ Ud,
                                               const float* __restrict__ ree,
                                               const float* __restrict__ reo,
                                               const float* __restrict__ roe,
                                               const float* __restrict__ roo,
                                               float* __restrict__ out, int n) {
  long pos = (long)blockIdx.x * 4 + threadIdx.x / 64;
  long total = (long)NB * n * n;
  if (pos >= total) return;
  int t = threadIdx.x & 63;
  int b = (int)(pos / (n * n));
  int rem = (int)(pos % (n * n));
  int xp = rem / n, yp = rem % n;
  long cs = (long)n * n * 64;
  long ib = (long)b * 9 * cs + (long)rem * 64 + t;
  float cat[18];
#pragma unroll
  for (int i = 0; i < 9; ++i) cat[i] = xc[ib + i * cs] + Us[ib + i * cs];
#pragma unroll
  for (int i = 0; i < 9; ++i) cat[9 + i] = Ud[ib + i * cs];
  int n2 = 2 * n;
  long ocs = (long)n2 * n2 * 64;
  long ob = (long)b * 9 * ocs + ((long)(2 * xp) * n2 + 2 * yp) * 64 + t;
  const float* rcw[4] = {ree, reo, roe, roo};
#pragma unroll
  for (int r = 0; r < 4; ++r) {
    int rx = r >> 1, ry = r & 1;
    long obb = ob + ((long)rx * n2 + ry) * 64;
    const float* wp = rcw[r];
#pragma unroll
    for (int o = 0; o < 9; ++o) {
      float s = 0.f;
#pragma unroll
      for (int i = 0; i < 18; ++i) s += cat[i] * wp[i * 9 + o];
      out[obb + o * ocs] = s;
    }
  }
}

extern "C" void kernel_launch(void* const* d_in, const int* in_sizes, int n_in, void* d_out,
                              int out_size, void* d_ws, size_t ws_size, hipStream_t stream) {
  (void)in_sizes; (void)n_in; (void)out_size; (void)ws_size;
  const float* x = (const float*)d_in[0];
  const float* aw[4] = {(const float*)d_in[1], (const float*)d_in[2], (const float*)d_in[3],
                        (const float*)d_in[4]};
  const float* a_low = (const float*)d_in[5];
  const float* a_lob = (const float*)d_in[6];
  const float* bw[4] = {(const float*)d_in[7], (const float*)d_in[8], (const float*)d_in[9],
                        (const float*)d_in[10]};
  const float* b_low = (const float*)d_in[11];
  const float* b_lob = (const float*)d_in[12];
  const float* cw[4] = {(const float*)d_in[13], (const float*)d_in[14], (const float*)d_in[15],
                        (const float*)d_in[16]};
  const float* c_low = (const float*)d_in[17];
  const float* c_lob = (const float*)d_in[18];
  const float* t0w = (const float*)d_in[19];
  const float* t0b = (const float*)d_in[20];
  const float* ecs = (const float*)d_in[21];
  const float* ecd = (const float*)d_in[22];
  const float* rcee = (const float*)d_in[23];
  const float* rceo = (const float*)d_in[24];
  const float* rcoe = (const float*)d_in[25];
  const float* rcoo = (const float*)d_in[26];

  float* ws = (float*)d_ws;
  size_t off = 0;
  float* twt = ws + off; off += 640;
  float* twx = ws + off; off += 6 * 640;
  float* s_a = ws + off; off += 9437184;
  float* s_b = ws + off; off += 9437184;
  float* Ud = ws + off; off += 12579840;
  float* Us = ws + off; off += 12579840;
  float* Zt_d = ws + off; off += 1474560;
  float* Zt_s = ws + off; off += 1474560;
  float* Zxy_d = ws + off; off += 144000;
  float* Zxy_s = ws + off; off += 144000;
  float* Z60 = ws + off; off += 1474560;
  float* Z61 = ws + off; off += 1474560;
  float* Z62 = ws + off; off += 1474560;

  static const long lvl_off[6] = {0, 9437184, 11796480, 12386304, 12533760, 12570624};

  k_init<<<1, 256, 0, stream>>>(twt, twx);

  const float* cur = x;
  for (int lev = 0; lev < 6; ++lev) {
    int n = 32 >> lev;
    int kn = n < 10 ? n : 10;
    float* s_cur = (lev & 1) ? s_b : s_a;
    int nblk = (NB * n * n + 3) / 4;
    float scale = 1.f / sqrtf((float)(n * n * 64));

    k_wavdft<<<nblk, 256, 0, stream>>>(cur, ecd, ecs, s_cur, Zt_d, Zt_s, twt, n, scale);
    k_bc<<<dim3(NB * NCH, 2), 256, 0, stream>>>(Zt_d, Zt_s, Zxy_d, Zxy_s, twx + lev * 640, n,
                                                kn);
    EfArgs ea;
    ea.in[0] = Zxy_d; ea.in[1] = Zxy_s; ea.in[2] = Zxy_d;
    for (int j = 0; j < 4; ++j) { ea.w[j] = aw[j]; ea.w[4 + j] = bw[j]; ea.w[8 + j] = cw[j]; }
    ea.out[0] = Z60; ea.out[1] = Z61; ea.out[2] = Z62;
    k_efmix<<<dim3(NB * NCH, 3), 256, 0, stream>>>(ea, twx + lev * 640, n, kn);
    k_gh3<<<nblk, 256, 0, stream>>>(Z60, Z61, Z62, a_low, a_lob, b_low, b_lob, c_low, c_lob,
                                    Ud + lvl_off[lev], Us + lvl_off[lev], twt, n, scale);
    cur = s_cur;
  }

  // coarsest-level conv (cur == s_b after lev 5); write into Zt_d (free now)
  k_t0<<<NB, 64, 0, stream>>>(cur, t0w, t0b, Zt_d);

  const float* rx = Zt_d;
  for (int i = 5; i >= 0; --i) {
    int nn = 32 >> i;
    float* dst = (i == 0) ? (float*)d_out : ((rx == s_a) ? s_b : s_a);
    k_recon<<<(NB * nn * nn + 3) / 4, 256, 0, stream>>>(rx, Us + lvl_off[i], Ud + lvl_off[i],
                                                        rcee, rceo, rcoe, rcoo, dst, nn);
    rx = dst;
  }
}

// Round 3
// 318.660 us; speedup vs baseline: 1.5815x; 1.2350x over previous
//
#include <hip/hip_runtime.h>
#include <hip/hip_fp16.h>
#include <math.h>

#define NB 16
#define NCH 9
#define PI2 6.28318530717958647692f

struct Levels {
  int n[6], kn[6];
  int zt_off[6];   // float elements
  int zxy_off[6];  // float elements
  int z6_off[6];   // half elements
  int u_off[6];    // half elements
  int gstart[7];   // cumulative block starts for gh3
  float scale[6];
};
struct WArgs {
  const float* w[12];
};

// ---------------- twiddle tables ----------------
__global__ __launch_bounds__(256) void k_init(float* __restrict__ twt, float* __restrict__ twx) {
  int tid = threadIdx.x;
  for (int i = tid; i < 5 * 64; i += 256) {
    int k = i >> 6, t = i & 63;
    float ang = (float)((k * t) & 63) * (PI2 / 64.f);
    float s, c;
    sincosf(ang, &s, &c);
    twt[2 * i] = c;
    twt[2 * i + 1] = s;
  }
  for (int lev = 0; lev < 6; ++lev) {
    int n = 32 >> lev;
    int kn = n < 10 ? n : 10;
    float* tx = twx + lev * 640;
    for (int i = tid; i < kn * n; i += 256) {
      int j = i / n, m = i % n;
      int k = (kn < 10) ? j : (j < 5 ? j : n - 10 + j);
      float ang = (float)((k * m) % n) * (PI2 / (float)n);
      float s, c;
      sincosf(ang, &s, &c);
      tx[2 * i] = c;
      tx[2 * i + 1] = s;
    }
  }
}

// ---------------- fused wavelet analysis + forward t-DFT (templated input type) -----------
template <typename T>
__global__ __launch_bounds__(256) void k_wavdft(const T* __restrict__ xin,
                                                const float* __restrict__ ecd,
                                                const float* __restrict__ ecs,
                                                __half* __restrict__ sout,
                                                float* __restrict__ Zd, float* __restrict__ Zs,
                                                const float* __restrict__ twt, int n,
                                                float scale) {
  __shared__ float V[72 * 65];
  __shared__ float tw[640];
  int tid = threadIdx.x;
  for (int i = tid; i < 640; i += 256) tw[i] = twt[i];
  long pos0 = (long)blockIdx.x * 4;
  long total = (long)NB * n * n;
  int p = tid >> 6, t = tid & 63;
  long pos = pos0 + p;
  if (pos < total) {
    int b = (int)(pos / (n * n));
    int rem = (int)(pos % (n * n));
    int xp = rem / n, yp = rem % n;
    int n2 = 2 * n;
    const T* xb = xin + (long)b * NCH * n2 * n2 * 64;
    float dacc[9], sacc[9];
#pragma unroll
    for (int o = 0; o < 9; ++o) { dacc[o] = 0.f; sacc[o] = 0.f; }
#pragma unroll
    for (int q = 0; q < 4; ++q) {
      int X = 2 * xp + (q >> 1), Y = 2 * yp + (q & 1);
      const T* xq = xb + ((long)X * n2 + Y) * 64 + t;
#pragma unroll
      for (int i = 0; i < 9; ++i) {
        float v = (float)xq[(long)i * n2 * n2 * 64];
#pragma unroll
        for (int o = 0; o < 9; ++o) {
          dacc[o] += v * ecd[(q * 9 + i) * 9 + o];
          sacc[o] += v * ecs[(q * 9 + i) * 9 + o];
        }
      }
    }
    long cs = (long)n * n * 64;
    __half* sp = sout + (long)b * NCH * cs + (long)rem * 64 + t;
#pragma unroll
    for (int o = 0; o < 9; ++o) {
      sp[o * cs] = __float2half(sacc[o]);
      V[(p * 18 + o) * 65 + t] = dacc[o];
      V[(p * 18 + 9 + o) * 65 + t] = sacc[o];
    }
  }
  __syncthreads();
  for (int idx = tid; idx < 360; idx += 256) {
    int k = idx % 5;
    int ch = (idx / 5) % 9;
    int ds = (idx / 45) & 1;
    int pp = idx / 90;
    long pos2 = pos0 + pp;
    if (pos2 >= total) continue;
    const float* vr = &V[(pp * 18 + ds * 9 + ch) * 65];
    float sr = 0.f, si = 0.f;
#pragma unroll 8
    for (int tt = 0; tt < 64; ++tt) {
      float v = vr[tt];
      sr += v * tw[2 * (k * 64 + tt)];
      si -= v * tw[2 * (k * 64 + tt) + 1];
    }
    int b = (int)(pos2 / (n * n));
    int rem = (int)(pos2 % (n * n));
    float* o = (ds ? Zs : Zd) + ((long)(b * 9 + ch) * n * n + rem) * 10 + 2 * k;
    o[0] = sr * scale;
    o[1] = si * scale;
  }
}

// ---------------- all-level forward y-DFT then x-DFT ----------------
// block: lev*288 + ds*144 + (b*9+ch)
__global__ __launch_bounds__(256) void k_bc_all(const float* __restrict__ Zt_d,
                                                const float* __restrict__ Zt_s,
                                                float* __restrict__ Zxy_d,
                                                float* __restrict__ Zxy_s,
                                                const float* __restrict__ twx_all, Levels lv) {
  __shared__ float S1[3200];
  __shared__ float tx[640];
  int lev = blockIdx.x / 288;
  int r = blockIdx.x % 288;
  int ds = r / 144, bc = r % 144;
  int n = lv.n[lev], kn = lv.kn[lev];
  int tid = threadIdx.x;
  const float* twx = twx_all + lev * 640;
  for (int i = tid; i < kn * n * 2; i += 256) tx[i] = twx[i];
  __syncthreads();
  const float* in = (ds ? Zt_s : Zt_d) + lv.zt_off[lev] + (long)bc * n * n * 10;
  float* out = (ds ? Zxy_s : Zxy_d) + lv.zxy_off[lev] + (long)bc * kn * kn * 10;
  int s1n = n * kn * 5;
  for (int idx = tid; idx < s1n; idx += 256) {
    int kz = idx % 5, jy = (idx / 5) % kn, x = idx / (5 * kn);
    float sr = 0.f, si = 0.f;
    const float* row = in + (long)x * n * 10 + 2 * kz;
    for (int y = 0; y < n; ++y) {
      float zr = row[y * 10], zi = row[y * 10 + 1];
      float c = tx[2 * (jy * n + y)], s = tx[2 * (jy * n + y) + 1];
      sr += zr * c + zi * s;
      si += zi * c - zr * s;
    }
    S1[2 * idx] = sr;
    S1[2 * idx + 1] = si;
  }
  __syncthreads();
  int s2n = kn * kn * 5;
  for (int idx = tid; idx < s2n; idx += 256) {
    int kz = idx % 5, jy = (idx / 5) % kn, jx = idx / (5 * kn);
    float sr = 0.f, si = 0.f;
    for (int x = 0; x < n; ++x) {
      float zr = S1[2 * ((x * kn + jy) * 5 + kz)], zi = S1[2 * ((x * kn + jy) * 5 + kz) + 1];
      float c = tx[2 * (jx * n + x)], s = tx[2 * (jx * n + x) + 1];
      sr += zr * c + zi * s;
      si += zi * c - zr * s;
    }
    out[2 * idx] = sr;
    out[2 * idx + 1] = si;
  }
}

// ---------------- all-level fused mode-mix + inverse expand x,y ----------------
// block: lev*432 + batch*144 + b*9 + o ; batch: 0=a(d),1=b(s),2=c(d)
__global__ __launch_bounds__(256) void k_efmix_all(const float* __restrict__ Zxy_d,
                                                   const float* __restrict__ Zxy_s,
                                                   __half* __restrict__ Z6a,
                                                   __half* __restrict__ Z6b,
                                                   __half* __restrict__ Z6c, WArgs wa,
                                                   const float* __restrict__ twx_all,
                                                   Levels lv) {
  __shared__ float zin[9000];
  __shared__ float zm[1000];
  __shared__ float S1[3200];
  __shared__ float tx[640];
  int lev = blockIdx.x / 432;
  int r = blockIdx.x % 432;
  int batch = r / 144;
  int rr = r % 144;
  int b = rr / 9, o = rr % 9;
  int n = lv.n[lev], kn = lv.kn[lev];
  int nm = kn * kn * 5;
  int tid = threadIdx.x;
  const float* twx = twx_all + lev * 640;
  const float* in = (batch == 1 ? Zxy_s : Zxy_d) + lv.zxy_off[lev] + (long)b * 9 * nm * 2;
  __half* out = (batch == 0 ? Z6a : batch == 1 ? Z6b : Z6c) + lv.z6_off[lev] +
                ((long)(b * 9 + o)) * n * n * 10;
  for (int i = tid; i < kn * n * 2; i += 256) tx[i] = twx[i];
  for (int i = tid; i < 9 * nm * 2; i += 256) zin[i] = in[i];
  __syncthreads();
  int l1 = (5 < n / 2 + 1) ? 5 : n / 2 + 1;
  for (int m = tid; m < nm; m += 256) {
    int kz = m % 5, jy = (m / 5) % kn, jx = m / (5 * kn);
    int kx = (kn < 10) ? jx : (jx < 5 ? jx : n - 10 + jx);
    int ky = (kn < 10) ? jy : (jy < 5 ? jy : n - 10 + jy);
    bool lx = kx < l1, hx = kx >= n - l1, ly = ky < l1, hy = ky >= n - l1;
    const float* wsel;
    int wx, wy;
    if (hx && hy) { wsel = wa.w[batch * 4 + 3]; wx = kx - (n - l1); wy = ky - (n - l1); }
    else if (lx && hy) { wsel = wa.w[batch * 4 + 2]; wx = kx; wy = ky - (n - l1); }
    else if (hx && ly) { wsel = wa.w[batch * 4 + 1]; wx = kx - (n - l1); wy = ky; }
    else { wsel = wa.w[batch * 4 + 0]; wx = kx; wy = ky; }
    const float* wp = wsel + o * 250 + wx * 50 + wy * 10 + kz * 2;
    float sr = 0.f, si = 0.f;
#pragma unroll
    for (int i = 0; i < 9; ++i) {
      float ar = zin[(i * nm + m) * 2], ai = zin[(i * nm + m) * 2 + 1];
      float wr = wp[i * 2250], wi = wp[i * 2250 + 1];
      sr += ar * wr - ai * wi;
      si += ar * wi + ai * wr;
    }
    zm[2 * m] = sr;
    zm[2 * m + 1] = si;
  }
  __syncthreads();
  int s1n = n * kn * 5;
  for (int idx = tid; idx < s1n; idx += 256) {
    int kz = idx % 5, jy = (idx / 5) % kn, x = idx / (5 * kn);
    float sr = 0.f, si = 0.f;
    for (int jx = 0; jx < kn; ++jx) {
      float zr = zm[2 * ((jx * kn + jy) * 5 + kz)], zi = zm[2 * ((jx * kn + jy) * 5 + kz) + 1];
      float c = tx[2 * (jx * n + x)], s = tx[2 * (jx * n + x) + 1];
      sr += zr * c - zi * s;
      si += zr * s + zi * c;
    }
    S1[2 * idx] = sr;
    S1[2 * idx + 1] = si;
  }
  __syncthreads();
  int s2n = n * n * 5;
  for (int idx = tid; idx < s2n; idx += 256) {
    int kz = idx % 5, y = (idx / 5) % n, x = idx / (5 * n);
    float sr = 0.f, si = 0.f;
    for (int jy = 0; jy < kn; ++jy) {
      float zr = S1[2 * ((x * kn + jy) * 5 + kz)], zi = S1[2 * ((x * kn + jy) * 5 + kz) + 1];
      float c = tx[2 * (jy * n + y)], s = tx[2 * (jy * n + y) + 1];
      sr += zr * c - zi * s;
      si += zr * s + zi * c;
    }
    __half2 h;
    h.x = __float2half(sr);
    h.y = __float2half(si);
    *reinterpret_cast<__half2*>(out + 2 * idx) = h;
  }
}

// ---------------- all-level inverse-t(c2r) + ReLU + lo conv for Ud and Us ----------------
__global__ __launch_bounds__(256) void k_gh3_all(const __half* __restrict__ Z6a,
                                                 const __half* __restrict__ Z6b,
                                                 const __half* __restrict__ Z6c,
                                                 const float* __restrict__ a_low,
                                                 const float* __restrict__ a_lob,
                                                 const float* __restrict__ b_low,
                                                 const float* __restrict__ b_lob,
                                                 const float* __restrict__ c_low,
                                                 const float* __restrict__ c_lob,
                                                 __half* __restrict__ Ud,
                                                 __half* __restrict__ Us,
                                                 const float* __restrict__ twt, Levels lv) {
  __shared__ float tw[640];
  __shared__ float zz[3][360];
  int tid = threadIdx.x;
  for (int i = tid; i < 640; i += 256) tw[i] = twt[i];
  int lev = 0;
  while (lev < 5 && (int)blockIdx.x >= lv.gstart[lev + 1]) ++lev;
  int n = lv.n[lev];
  float scale = lv.scale[lev];
  long pos0 = (long)(blockIdx.x - lv.gstart[lev]) * 4;
  long total = (long)NB * n * n;
  const __half* zbuf[3] = {Z6a + lv.z6_off[lev], Z6b + lv.z6_off[lev], Z6c + lv.z6_off[lev]};
  for (int i = tid; i < 3 * 360; i += 256) {
    int bi = i / 360, rest = i % 360;
    int p = rest / 90, rr = rest % 90;
    long pos = pos0 + p;
    if (pos < total) {
      int b = (int)(pos / (n * n));
      int rem = (int)(pos % (n * n));
      int ch = rr / 10, zi = rr % 10;
      zz[bi][rest] = __half2float(zbuf[bi][((long)(b * 9 + ch) * n * n + rem) * 10 + zi]);
    }
  }
  __syncthreads();
  int p = tid / 64, t = tid & 63;
  long pos = pos0 + p;
  if (pos >= total) return;
  int b = (int)(pos / (n * n));
  int rem = (int)(pos % (n * n));
  float rva[9], rvb[9], rvc[9];
#pragma unroll
  for (int i = 0; i < 9; ++i) {
    const float* za = &zz[0][p * 90 + i * 10];
    const float* zb = &zz[1][p * 90 + i * 10];
    const float* zc = &zz[2][p * 90 + i * 10];
    float va = za[0], vb = zb[0], vc = zc[0];
#pragma unroll
    for (int k = 1; k < 5; ++k) {
      float c = tw[2 * (k * 64 + t)], s = tw[2 * (k * 64 + t) + 1];
      va += 2.f * (za[2 * k] * c - za[2 * k + 1] * s);
      vb += 2.f * (zb[2 * k] * c - zb[2 * k + 1] * s);
      vc += 2.f * (zc[2 * k] * c - zc[2 * k + 1] * s);
    }
    rva[i] = fmaxf(va * scale, 0.f);
    rvb[i] = fmaxf(vb * scale, 0.f);
    rvc[i] = fmaxf(vc * scale, 0.f);
  }
  long cs = (long)n * n * 64;
  long ob = (long)b * 9 * cs + (long)rem * 64 + t;
  __half* ud = Ud + lv.u_off[lev];
  __half* us = Us + lv.u_off[lev];
#pragma unroll
  for (int o = 0; o < 9; ++o) {
    float du = a_lob[o] + b_lob[o];
    float usv = c_lob[o];
#pragma unroll
    for (int i = 0; i < 9; ++i) {
      du += a_low[o * 9 + i] * rva[i] + b_low[o * 9 + i] * rvb[i];
      usv += c_low[o * 9 + i] * rvc[i];
    }
    ud[ob + o * cs] = __float2half(du);
    us[ob + o * cs] = __float2half(usv);
  }
}

// ---------------- coarsest-level T0 1x1 conv ----------------
__global__ __launch_bounds__(64) void k_t0(const __half* __restrict__ sin_,
                                           const float* __restrict__ w,
                                           const float* __restrict__ bias,
                                           float* __restrict__ out) {
  int b = blockIdx.x, t = threadIdx.x;
  float v[9];
#pragma unroll
  for (int i = 0; i < 9; ++i) v[i] = __half2float(sin_[((long)b * 9 + i) * 64 + t]);
#pragma unroll
  for (int o = 0; o < 9; ++o) {
    float s = bias[o];
#pragma unroll
    for (int i = 0; i < 9; ++i) s += w[o * 9 + i] * v[i];
    out[((long)b * 9 + o) * 64 + t] = s;
  }
}

// ---------------- reconstruction ----------------
__global__ __launch_bounds__(256) void k_recon(const float* __restrict__ xc,
                                               const __half* __restrict__ Us,
                                               const __half* __restrict__ Ud,
                                               const float* __restrict__ ree,
                                               const float* __restrict__ reo,
                                               const float* __restrict__ roe,
                                               const float* __restrict__ roo,
                                               float* __restrict__ out, int n) {
  long pos = (long)blockIdx.x * 4 + threadIdx.x / 64;
  long total = (long)NB * n * n;
  if (pos >= total) return;
  int t = threadIdx.x & 63;
  int b = (int)(pos / (n * n));
  int rem = (int)(pos % (n * n));
  int xp = rem / n, yp = rem % n;
  long cs = (long)n * n * 64;
  long ib = (long)b * 9 * cs + (long)rem * 64 + t;
  float cat[18];
#pragma unroll
  for (int i = 0; i < 9; ++i) cat[i] = xc[ib + i * cs] + __half2float(Us[ib + i * cs]);
#pragma unroll
  for (int i = 0; i < 9; ++i) cat[9 + i] = __half2float(Ud[ib + i * cs]);
  int n2 = 2 * n;
  long ocs = (long)n2 * n2 * 64;
  long ob = (long)b * 9 * ocs + ((long)(2 * xp) * n2 + 2 * yp) * 64 + t;
  const float* rcw[4] = {ree, reo, roe, roo};
#pragma unroll
  for (int r = 0; r < 4; ++r) {
    int rx = r >> 1, ry = r & 1;
    long obb = ob + ((long)rx * n2 + ry) * 64;
    const float* wp = rcw[r];
#pragma unroll
    for (int o = 0; o < 9; ++o) {
      float s = 0.f;
#pragma unroll
      for (int i = 0; i < 18; ++i) s += cat[i] * wp[i * 9 + o];
      out[obb + o * ocs] = s;
    }
  }
}

extern "C" void kernel_launch(void* const* d_in, const int* in_sizes, int n_in, void* d_out,
                              int out_size, void* d_ws, size_t ws_size, hipStream_t stream) {
  (void)in_sizes; (void)n_in; (void)out_size; (void)ws_size;
  const float* x = (const float*)d_in[0];
  const float* aw[4] = {(const float*)d_in[1], (const float*)d_in[2], (const float*)d_in[3],
                        (const float*)d_in[4]};
  const float* a_low = (const float*)d_in[5];
  const float* a_lob = (const float*)d_in[6];
  const float* bw[4] = {(const float*)d_in[7], (const float*)d_in[8], (const float*)d_in[9],
                        (const float*)d_in[10]};
  const float* b_low = (const float*)d_in[11];
  const float* b_lob = (const float*)d_in[12];
  const float* cw[4] = {(const float*)d_in[13], (const float*)d_in[14], (const float*)d_in[15],
                        (const float*)d_in[16]};
  const float* c_low = (const float*)d_in[17];
  const float* c_lob = (const float*)d_in[18];
  const float* t0w = (const float*)d_in[19];
  const float* t0b = (const float*)d_in[20];
  const float* ecs = (const float*)d_in[21];
  const float* ecd = (const float*)d_in[22];
  const float* rcee = (const float*)d_in[23];
  const float* rceo = (const float*)d_in[24];
  const float* rcoe = (const float*)d_in[25];
  const float* rcoo = (const float*)d_in[26];

  // ---- level descriptor ----
  Levels lv;
  {
    int zt = 0, zxy = 0, gh = 0;
    static const int uoff[6] = {0, 9437184, 11796480, 12386304, 12533760, 12570624};
    for (int lev = 0; lev < 6; ++lev) {
      int n = 32 >> lev;
      int kn = n < 10 ? n : 10;
      lv.n[lev] = n;
      lv.kn[lev] = kn;
      lv.zt_off[lev] = zt;
      lv.zxy_off[lev] = zxy;
      lv.z6_off[lev] = zt;  // same element counts as Zt
      lv.u_off[lev] = uoff[lev];
      lv.gstart[lev] = gh;
      lv.scale[lev] = 1.f / sqrtf((float)(n * n * 64));
      zt += NB * 9 * n * n * 10;
      zxy += NB * 9 * kn * kn * 10;
      gh += (NB * n * n + 3) / 4;
    }
    lv.gstart[6] = gh;
  }

  // ---- workspace layout ----
  char* base = (char*)d_ws;
  size_t ob = 0;
  auto allocF = [&](size_t nelem) { float* p = (float*)(base + ob); ob += nelem * 4; return p; };
  auto allocH = [&](size_t nelem) { __half* p = (__half*)(base + ob); ob += ((nelem + 1) & ~(size_t)1) * 2; return p; };
  float* twt = allocF(640);
  float* twx = allocF(3840);
  float* Zt_d = allocF(1965600);
  float* Zt_s = allocF(1965600);
  float* Zxy_d = allocF(410400);
  float* Zxy_s = allocF(410400);
  float* rec_a = allocF(2359296);
  float* rec_b = allocF(9437184);
  __half* s_a = allocH(9437184);
  __half* s_b = allocH(9437184);
  __half* Z6a = allocH(1965600);
  __half* Z6b = allocH(1965600);
  __half* Z6c = allocH(1965600);
  __half* Ud = allocH(12579840);
  __half* Us = allocH(12579840);

  k_init<<<1, 256, 0, stream>>>(twt, twx);

  // ---- 6 serial wavelet+tDFT levels ----
  for (int lev = 0; lev < 6; ++lev) {
    int n = 32 >> lev;
    int nblk = (NB * n * n + 3) / 4;
    __half* s_cur = (lev & 1) ? s_b : s_a;
    float* ztd = Zt_d + lv.zt_off[lev];
    float* zts = Zt_s + lv.zt_off[lev];
    if (lev == 0)
      k_wavdft<float><<<nblk, 256, 0, stream>>>(x, ecd, ecs, s_cur, ztd, zts, twt, n,
                                                lv.scale[lev]);
    else
      k_wavdft<__half><<<nblk, 256, 0, stream>>>((lev & 1) ? s_a : s_b, ecd, ecs, s_cur, ztd,
                                                 zts, twt, n, lv.scale[lev]);
  }

  // ---- batched spectral branch over all levels ----
  k_bc_all<<<6 * 288, 256, 0, stream>>>(Zt_d, Zt_s, Zxy_d, Zxy_s, twx, lv);
  WArgs wa;
  for (int j = 0; j < 4; ++j) { wa.w[j] = aw[j]; wa.w[4 + j] = bw[j]; wa.w[8 + j] = cw[j]; }
  k_efmix_all<<<6 * 432, 256, 0, stream>>>(Zxy_d, Zxy_s, Z6a, Z6b, Z6c, wa, twx, lv);
  k_gh3_all<<<lv.gstart[6], 256, 0, stream>>>(Z6a, Z6b, Z6c, a_low, a_lob, b_low, b_lob, c_low,
                                              c_lob, Ud, Us, twt, lv);

  // ---- coarsest-level conv (s after lev5 is s_b) ----
  k_t0<<<NB, 64, 0, stream>>>(s_b, t0w, t0b, rec_a);

  // ---- serial reconstruction chain ----
  const float* rx = rec_a;
  for (int i = 5; i >= 0; --i) {
    int nn = 32 >> i;
    float* dst = (i == 0) ? (float*)d_out : ((rx == rec_a) ? rec_b : rec_a);
    k_recon<<<(NB * nn * nn + 3) / 4, 256, 0, stream>>>(rx, Us + lv.u_off[i], Ud + lv.u_off[i],
                                                        rcee, rceo, rcoe, rcoo, dst, nn);
    rx = dst;
  }
}